// Round 8
// baseline (82.737 us; speedup 1.0000x reference)
//
#include <hip/hip_runtime.h>

// Problem constants (match reference)
constexpr int N = 64, C = 256, H = 64, W = 64, P = 1024;
constexpr int PLANE   = H * W;    // 4096 floats = 16 KB
constexpr int GC      = 16;       // channel-planes per block
constexpr int THREADS = 256;      // 4 waves
constexpr int PPT     = 4;        // points per thread (1024/256)
constexpr int NBUF    = 5;        // ring of 5 -> prefetch distance 4

typedef float v4f __attribute__((ext_vector_type(4)));

// Evolution of round 7 (82us, latency-convoy-bound: VALU 2.5%, HBM 11%):
//  - prefetch distance 4 (ring-5): issue window ~4 compute phases (~2000cy)
//    >> ~900cy HBM-miss latency, so the per-plane vmcnt wait at the barrier
//    should be ~free even for the slowest wave (convoy killer).
//  - GC=16: one block owns 16 planes -> coords/ctx prologue and store
//    epilogue amortized 2x vs round 7; grid 1024.
//  - one barrier + one counted vmcnt + one lgkmcnt drain per plane.
//  - 80 KB LDS -> 2 blocks/CU co-resident for TLP on top.
// vmcnt ledger: exactly 4 global_load_lds per wave per stage; outstanding at
// iter-k top = 4*(min(k+3,GC-1)-k+1): 16/12/8/4 -> wait 12/8/4/0.
// Buffer-reuse hazard: stage(k+4) writes buf[(k+4)%5]=buf[(k-1)%5]; every
// wave drained its plane-(k-1) ds_reads (lgkmcnt(0)) before iter-k's barrier.
__device__ __forceinline__ void stage_plane(const float* __restrict__ src,
                                            float* __restrict__ dst, int t) {
    const int tb = t & ~63;            // wave-uniform LDS base (linear dest)
    #pragma unroll
    for (int i = 0; i < 4; ++i) {
        const int j  = (i << 8) + t;   // per-lane float4 index 0..1023
        const int jb = (i << 8) + tb;
        __builtin_amdgcn_global_load_lds(
            (const __attribute__((address_space(1))) void*)(src + (j << 2)),
            (__attribute__((address_space(3))) void*)(dst + (jb << 2)),
            16, 0, 0);
    }
}

__global__ __launch_bounds__(THREADS) void progressive_sample_kernel(
    const float* __restrict__ inp,     // [N,C,H,W]
    const float* __restrict__ point,   // [N,P,2] (y,x)
    const float* __restrict__ offset,  // [N,P,2]
    float* __restrict__ out)           // [N,P,C]
{
    __shared__ __align__(16) float buf[NBUF][PLANE];   // 80 KB

    const int b = blockIdx.x;
    const int n = b >> 4;              // 16 channel-groups per image
    const int g = b & 15;
    const int t = threadIdx.x;
    const int chan0 = g * GC;

    const float* src = inp + ((size_t)n * C + chan0) * PLANE;

    // --- prologue: coord loads first, then 4 plane-stages in flight ---
    float2 pt_[PPT], of_[PPT];
    #pragma unroll
    for (int i = 0; i < PPT; ++i) {
        const int p = (i << 8) + t;
        pt_[i] = ((const float2*)point )[((size_t)n << 10) + p];
        of_[i] = ((const float2*)offset)[((size_t)n << 10) + p];
    }
    #pragma unroll
    for (int k = 0; k < 4; ++k)
        stage_plane(src + (size_t)k * PLANE, buf[k], t);

    // ctx per point (consumes coords; compiler's auto-wait retires the coord
    // loads while the 16 stage loads stay in flight)
    int   i00[PPT], i01[PPT], i10[PPT], i11[PPT];
    float w00[PPT], w01[PPT], w10[PPT], w11[PPT];
    #pragma unroll
    for (int i = 0; i < PPT; ++i) {
        const float y = pt_[i].x + of_[i].x;
        const float x = pt_[i].y + of_[i].y;
        const float y0f = floorf(y), x0f = floorf(x);
        const float ly = y - y0f, lx = x - x0f;
        const float hy = 1.0f - ly, hx = 1.0f - lx;
        const int y0 = (int)y0f, x0 = (int)x0f, y1 = y0 + 1, x1 = x0 + 1;
        const bool vy0 = (unsigned)y0 < (unsigned)H, vy1 = (unsigned)y1 < (unsigned)H;
        const bool vx0 = (unsigned)x0 < (unsigned)W, vx1 = (unsigned)x1 < (unsigned)W;
        const int yc0 = min(max(y0, 0), H - 1), yc1 = min(max(y1, 0), H - 1);
        const int xc0 = min(max(x0, 0), W - 1), xc1 = min(max(x1, 0), W - 1);
        i00[i] = yc0 * W + xc0; i01[i] = yc0 * W + xc1;
        i10[i] = yc1 * W + xc0; i11[i] = yc1 * W + xc1;
        w00[i] = (vy0 && vx0) ? hy * hx : 0.0f;
        w01[i] = (vy0 && vx1) ? hy * lx : 0.0f;
        w10[i] = (vy1 && vx0) ? ly * hx : 0.0f;
        w11[i] = (vy1 && vx1) ? ly * lx : 0.0f;
    }

    float acc[PPT][GC];                // statically indexed -> registers

    #pragma unroll
    for (int k = 0; k < GC; ++k) {
        // wait until stage(k) landed; keep stages k+1..k+3 in flight
        if (k <= GC - 4) {
            asm volatile("s_waitcnt vmcnt(12)" ::: "memory");
        } else if (k == GC - 3) {
            asm volatile("s_waitcnt vmcnt(8)" ::: "memory");
        } else if (k == GC - 2) {
            asm volatile("s_waitcnt vmcnt(4)" ::: "memory");
        } else {
            asm volatile("s_waitcnt vmcnt(0)" ::: "memory");
        }
        __builtin_amdgcn_sched_barrier(0);
        __builtin_amdgcn_s_barrier();      // stage(k) visible to all waves;
                                           // all plane-(k-1) reads drained
        __builtin_amdgcn_sched_barrier(0);

        if (k + 4 < GC)                    // distance-4 prefetch
            stage_plane(src + (size_t)(k + 4) * PLANE, buf[(k + 4) % NBUF], t);

        const float* __restrict__ bk = buf[k % NBUF];
        #pragma unroll
        for (int i = 0; i < PPT; ++i) {
            acc[i][k] = bk[i00[i]] * w00[i] + bk[i01[i]] * w01[i]
                      + bk[i10[i]] * w10[i] + bk[i11[i]] * w11[i];
        }

        asm volatile("s_waitcnt lgkmcnt(0)" ::: "memory");   // my reads done
        __builtin_amdgcn_sched_barrier(0);
    }

    // --- stores: thread owns the full 64 B line (16 ch) of its point ---
    // (round-6 measured WRITE_SIZE exactly 64 MB with this pattern)
    #pragma unroll
    for (int i = 0; i < PPT; ++i) {
        float* o = out + (((size_t)n << 10) + ((i << 8) + t)) * C + chan0;
        #pragma unroll
        for (int q = 0; q < 4; ++q) {
            v4f v = { acc[i][4*q+0], acc[i][4*q+1], acc[i][4*q+2], acc[i][4*q+3] };
            *(v4f*)(o + 4 * q) = v;
        }
    }
}

extern "C" void kernel_launch(void* const* d_in, const int* in_sizes, int n_in,
                              void* d_out, int out_size, void* d_ws, size_t ws_size,
                              hipStream_t stream) {
    const float* inp    = (const float*)d_in[0];
    const float* point  = (const float*)d_in[1];
    const float* offset = (const float*)d_in[2];
    float* out = (float*)d_out;

    progressive_sample_kernel<<<N * (C / GC), THREADS, 0, stream>>>(
        inp, point, offset, out);
}

// Round 9
// 79.315 us; speedup vs baseline: 1.0431x; 1.0431x over previous
//
#include <hip/hip_runtime.h>

// Problem constants (match reference)
constexpr int N = 64, C = 256, H = 64, W = 64, P = 1024;
constexpr int PLANE   = H * W;    // 4096 floats = 16 KB
constexpr int GC      = 8;        // channel-planes per block
constexpr int THREADS = 1024;     // 16 waves -> PPT=1, tiny VGPR state
constexpr int NBUF    = 4;        // ring of 4 -> prefetch distance 3

typedef float v4f __attribute__((ext_vector_type(4)));

// Rounds 6-8 all land at 82-89 us regardless of pipeline depth/barrier count
// -> not latency-bound; effective staging rate ~3.3 TB/s (half of copy rate).
// Hypothesis: stream shape. This version maximizes it:
//  - 1024 threads/block, 64 KB LDS, ~40 VGPR -> 2 blocks/CU = 32 waves/CU
//    (100% occupancy; prior rounds ran 8-12 waves/CU).
//  - stage quantum = ONE global_load_lds per wave per plane (1 KB/wave);
//    per-phase per-wave compute ~100 cyc -> kernel is stream-shaped like the
//    6.3 TB/s copy benchmark, with in-flight demand ~96 KB/CU.
//  - ring-4, distance-3 counted vmcnt (ledger below), one s_barrier/phase.
// vmcnt ledger (1 load/wave/plane): prologue issues planes {0,1,2}. Phase k
// top: outstanding = stages k..min(k+2,7) -> wait vmcnt(2) for k<=5, 1 at
// k=6, 0 at k=7. After barrier, phase k issues stage(k+3) (k<=4), which
// overwrites buf[(k-1)&3]: all plane-(k-1) reads were lgkm-drained at end of
// phase k-1 and the top-of-k barrier orders that block-wide -> safe.
__device__ __forceinline__ void stage_plane(const float* __restrict__ src,
                                            float* __restrict__ dst, int t) {
    const int tb = t & ~63;            // wave-uniform LDS base (linear dest)
    __builtin_amdgcn_global_load_lds(
        (const __attribute__((address_space(1))) void*)(src + (t << 2)),
        (__attribute__((address_space(3))) void*)(dst + (tb << 2)),
        16, 0, 0);
}

__global__ __launch_bounds__(THREADS, 2) void progressive_sample_kernel(
    const float* __restrict__ inp,     // [N,C,H,W]
    const float* __restrict__ point,   // [N,P,2] (y,x)
    const float* __restrict__ offset,  // [N,P,2]
    float* __restrict__ out)           // [N,P,C]
{
    __shared__ __align__(16) float buf[NBUF][PLANE];   // 64 KB -> 2 blocks/CU

    const int b = blockIdx.x;
    const int n = b >> 5;              // 32 channel-groups of 8 per image
    const int g = b & 31;
    const int t = threadIdx.x;
    const int chan0 = g * GC;

    const float* src = inp + ((size_t)n * C + chan0) * PLANE;

    // --- prologue: coord loads, then 3 plane-stages in flight ---
    const float2 pt2 = ((const float2*)point )[((size_t)n << 10) + t];
    const float2 of2 = ((const float2*)offset)[((size_t)n << 10) + t];
    stage_plane(src,             buf[0], t);
    stage_plane(src + PLANE,     buf[1], t);
    stage_plane(src + 2 * PLANE, buf[2], t);

    // ctx for this thread's single point (compiler auto-waits the coord
    // loads with the 3 stage loads still in flight)
    const float y = pt2.x + of2.x;
    const float x = pt2.y + of2.y;
    const float y0f = floorf(y), x0f = floorf(x);
    const float ly = y - y0f, lx = x - x0f;
    const float hy = 1.0f - ly, hx = 1.0f - lx;
    const int y0 = (int)y0f, x0 = (int)x0f, y1 = y0 + 1, x1 = x0 + 1;
    const bool vy0 = (unsigned)y0 < (unsigned)H, vy1 = (unsigned)y1 < (unsigned)H;
    const bool vx0 = (unsigned)x0 < (unsigned)W, vx1 = (unsigned)x1 < (unsigned)W;
    const int yc0 = min(max(y0, 0), H - 1), yc1 = min(max(y1, 0), H - 1);
    const int xc0 = min(max(x0, 0), W - 1), xc1 = min(max(x1, 0), W - 1);
    const int i00 = yc0 * W + xc0, i01 = yc0 * W + xc1;
    const int i10 = yc1 * W + xc0, i11 = yc1 * W + xc1;
    const float w00 = (vy0 && vx0) ? hy * hx : 0.0f;
    const float w01 = (vy0 && vx1) ? hy * lx : 0.0f;
    const float w10 = (vy1 && vx0) ? ly * hx : 0.0f;
    const float w11 = (vy1 && vx1) ? ly * lx : 0.0f;

    float acc[GC];                     // statically indexed -> registers

    #pragma unroll
    for (int k = 0; k < GC; ++k) {
        // wait stage(k) landed; keep later stages in flight (counted, never
        // drain-0 in steady state)
        if (k <= GC - 3) {
            asm volatile("s_waitcnt vmcnt(2)" ::: "memory");
        } else if (k == GC - 2) {
            asm volatile("s_waitcnt vmcnt(1)" ::: "memory");
        } else {
            asm volatile("s_waitcnt vmcnt(0)" ::: "memory");
        }
        __builtin_amdgcn_sched_barrier(0);
        __builtin_amdgcn_s_barrier();      // stage(k) visible block-wide;
                                           // plane-(k-1) reads all drained
        __builtin_amdgcn_sched_barrier(0);

        if (k + 3 < GC)                    // distance-3 prefetch
            stage_plane(src + (size_t)(k + 3) * PLANE, buf[(k + 3) & 3], t);

        const float* __restrict__ bk = buf[k & 3];
        acc[k] = bk[i00] * w00 + bk[i01] * w01
               + bk[i10] * w10 + bk[i11] * w11;

        asm volatile("s_waitcnt lgkmcnt(0)" ::: "memory");   // my reads done
        __builtin_amdgcn_sched_barrier(0);
    }

    // --- store: thread owns 32 B (8 ch) of its point's line; plain cached
    //     stores -> L2 merges lines regardless of per-lane granularity
    //     (NT would stream 16 B sectors unmerged -> round-4's 3x amp) ---
    float* o = out + (((size_t)n << 10) + t) * C + chan0;
    v4f v0 = { acc[0], acc[1], acc[2], acc[3] };
    v4f v1 = { acc[4], acc[5], acc[6], acc[7] };
    *(v4f*)o       = v0;
    *(v4f*)(o + 4) = v1;
}

extern "C" void kernel_launch(void* const* d_in, const int* in_sizes, int n_in,
                              void* d_out, int out_size, void* d_ws, size_t ws_size,
                              hipStream_t stream) {
    const float* inp    = (const float*)d_in[0];
    const float* point  = (const float*)d_in[1];
    const float* offset = (const float*)d_in[2];
    float* out = (float*)d_out;

    progressive_sample_kernel<<<N * (C / GC), THREADS, 0, stream>>>(
        inp, point, offset, out);
}